// Round 7
// baseline (396.428 us; speedup 1.0000x reference)
//
#include <hip/hip_runtime.h>
#include <math.h>

// Problem constants (B=4,S=2048,D=1024,H=2048,E=8, top-2)
#define T_TOKENS 8192
#define DIM      1024
#define HDIM     2048
#define NEXP     8
#define NASSIGN  16384   // T_TOKENS * 2
#define RTOK     16      // tokens per router block
#define RBLOCKS  (T_TOKENS / RTOK)
#define BK       64      // GEMM K-tile
#define SWSTRIDE 1028    // router sW leading dim (breaks 8-way store conflict)
#define TBLOCKS  8192    // transpose blocks in prep_kernel
#define NFILL    (T_TOKENS / 256)   // 32 fill blocks
#define NWARM    64                 // Xb warm blocks appended to fill grid

typedef __attribute__((ext_vector_type(8))) short short8;
typedef __attribute__((ext_vector_type(4))) float floatx4;
typedef __attribute__((address_space(3))) void lds_void;
typedef const __attribute__((address_space(1))) void gbl_void;

__device__ __forceinline__ unsigned short f2bf(float f) {
  unsigned u = __float_as_uint(f);
  u += 0x7fffu + ((u >> 16) & 1u);   // RNE
  return (unsigned short)(u >> 16);
}
__device__ __forceinline__ float bf2f(unsigned short h) {
  return __uint_as_float(((unsigned)h) << 16);
}

// fast GELU: v * sigmoid(1.5958*(v + 0.044715 v^3)); max abs err ~1e-3 vs erf
__device__ __forceinline__ float gelu_fast(float v) {
  float u = 1.5957691216057308f * v * fmaf(0.044715f * v, v, 1.0f);
  return v / (1.f + __expf(-u));
}

// ------- prep: fused {router FIRST} + {W1,W2 transpose+convert} -----------
// R5/R6 A/B resolved: router is a ~20us VALU-heavy job. Placed LAST it runs
// solo (serialized tail, R6: total +20us elsewhere); placed FIRST it hides
// fully under the BW-bound transpose, but the ~300MB transpose stream then
// evicts the early-written Xb from L3 -> GEMM1 gather eats HBM latency
// (R5: GEMM1 91.6->108). Resolution: router FIRST + an Xb L3 re-warm in the
// fill dispatch (below) restores both.
__global__ __launch_bounds__(256) void prep_kernel(
    const float* __restrict__ W1, const float* __restrict__ W2,
    unsigned short* __restrict__ W1T, unsigned short* __restrict__ W2T,
    const float* __restrict__ x, const float* __restrict__ Wr,
    const float* __restrict__ br, unsigned short* __restrict__ Xb,
    int* __restrict__ topk_i, float* __restrict__ topk_w,
    int* __restrict__ pc_partial,      // [RBLOCKS][NEXP]
    float* __restrict__ pp_partial) {  // [RBLOCKS][NEXP]
  __shared__ float smem[NEXP * SWSTRIDE + 64];  // 33.2 KB union
  int rb = blockIdx.x;
  int tid = threadIdx.x;

  if (rb >= RBLOCKS) {
    // ---------------- transpose path ----------------
    float (*tile)[65] = (float(*)[65])smem;
    int b = rb - RBLOCKS;
    const float* inp; unsigned short* outp; int R, C, r0, c0;
    if (b < 4096) {                       // W1: R=1024, C=2048; 512 tiles/exp
      int e = b >> 9, t = b & 511;
      R = DIM; C = HDIM;
      c0 = (t & 31) * 64; r0 = (t >> 5) * 64;
      long eb = (long)e * R * C;
      inp = W1 + eb; outp = W1T + eb;
    } else {                              // W2: R=2048, C=1024
      int bb = b - 4096;
      int e = bb >> 9, t = bb & 511;
      R = HDIM; C = DIM;
      c0 = (t & 15) * 64; r0 = (t >> 4) * 64;
      long eb = (long)e * R * C;
      inp = W2 + eb; outp = W2T + eb;
    }
    int rr = tid >> 4, c4 = (tid & 15) * 4;
    #pragma unroll
    for (int i = 0; i < 4; i++) {
      float4 v = *(const float4*)(inp + (long)(r0 + rr + i * 16) * C + c0 + c4);
      tile[rr + i * 16][c4 + 0] = v.x;
      tile[rr + i * 16][c4 + 1] = v.y;
      tile[rr + i * 16][c4 + 2] = v.z;
      tile[rr + i * 16][c4 + 3] = v.w;
    }
    __syncthreads();
    // 512 short8 stores, 2/thread: s -> col c = s>>3, row-block rq = (s&7)*8
    #pragma unroll
    for (int j = 0; j < 2; j++) {
      int s = tid * 2 + j;
      int c = s >> 3;
      int rq = (s & 7) * 8;
      short8 ov;
      #pragma unroll
      for (int i = 0; i < 8; i++) ov[i] = (short)f2bf(tile[rq + i][c]);
      *(short8*)(outp + (long)(c0 + c) * R + r0 + rq) = ov;
    }
    return;
  }

  // ---------------- router path (FIRST: hidden under transpose) ----------
  int bid = rb;
  float* sW = smem;                                   // [NEXP*SWSTRIDE]
  float (*sP)[NEXP] = (float(*)[NEXP])(smem + NEXP * SWSTRIDE);
  int   (*sC)[NEXP] = (int(*)[NEXP])(smem + NEXP * SWSTRIDE + 32);
  for (int i = tid; i < NEXP * DIM; i += 256)   // coalesced load, spread banks
    sW[(i & 7) * SWSTRIDE + (i >> 3)] = Wr[i];
  __syncthreads();
  int wid = tid >> 6, lane = tid & 63;
  float pacc[NEXP]; int cacc[NEXP];
  #pragma unroll
  for (int e = 0; e < NEXP; e++) { pacc[e] = 0.f; cacc[e] = 0; }
  #pragma unroll
  for (int it = 0; it < 4; it++) {
    int t = bid * RTOK + wid * 4 + it;
    const float* xp = x + (long)t * DIM;
    unsigned short* xbp = Xb + (long)t * DIM;
    float acc[NEXP];
    #pragma unroll
    for (int e = 0; e < NEXP; e++) acc[e] = 0.f;
    #pragma unroll
    for (int i = 0; i < 4; i++) {
      int off = i * 256 + lane * 4;
      float4 v = *(const float4*)(xp + off);
      ushort4 o;
      o.x = f2bf(v.x); o.y = f2bf(v.y); o.z = f2bf(v.z); o.w = f2bf(v.w);
      *(ushort4*)(xbp + off) = o;
      #pragma unroll
      for (int e = 0; e < NEXP; e++) {
        float4 w = *(const float4*)&sW[e * SWSTRIDE + off];
        acc[e] += v.x * w.x + v.y * w.y + v.z * w.z + v.w * w.w;
      }
    }
    #pragma unroll
    for (int e = 0; e < NEXP; e++) {
      #pragma unroll
      for (int off = 32; off; off >>= 1) acc[e] += __shfl_xor(acc[e], off, 64);
    }
    if (lane == 0) {
      float l[NEXP];
      #pragma unroll
      for (int e = 0; e < NEXP; e++) l[e] = acc[e] + br[e];
      float mx = l[0];
      #pragma unroll
      for (int e = 1; e < NEXP; e++) mx = fmaxf(mx, l[e]);
      float p[NEXP], s = 0.f;
      #pragma unroll
      for (int e = 0; e < NEXP; e++) { p[e] = __expf(l[e] - mx); s += p[e]; }
      float inv = 1.f / s;
      #pragma unroll
      for (int e = 0; e < NEXP; e++) p[e] *= inv;
      // top-2, lowest index wins ties (matches lax.top_k)
      int i1 = 0;
      #pragma unroll
      for (int e = 1; e < NEXP; e++) if (l[e] > l[i1]) i1 = e;
      int i2 = (i1 == 0) ? 1 : 0;
      #pragma unroll
      for (int e = 0; e < NEXP; e++)
        if (e != i1 && l[e] > l[i2]) i2 = e;
      float s2 = fmaxf(p[i1] + p[i2], 1e-9f);
      topk_i[2 * t] = i1; topk_i[2 * t + 1] = i2;
      topk_w[2 * t] = p[i1] / s2; topk_w[2 * t + 1] = p[i2] / s2;
      #pragma unroll
      for (int e = 0; e < NEXP; e++) {
        pacc[e] += p[e];
        cacc[e] += (e == i1 || e == i2) ? 1 : 0;
      }
    }
  }
  if (lane == 0) {
    #pragma unroll
    for (int e = 0; e < NEXP; e++) { sP[wid][e] = pacc[e]; sC[wid][e] = cacc[e]; }
  }
  __syncthreads();
  if (tid < NEXP) {
    float ps = 0.f; int cs = 0;
    #pragma unroll
    for (int w = 0; w < 4; w++) { ps += sP[w][tid]; cs += sC[w][tid]; }
    pp_partial[bid * NEXP + tid] = ps;
    pc_partial[bid * NEXP + tid] = cs;
  }
}

// ------ fill token lists (blocks 0..31) + Xb L3 re-warm (blocks 32..95) ---
// Fill: deterministic prefix slots, no atomics, no memset (R5, kept).
// Warm: 64 blocks stream-read all 16 MB of Xb. The transpose stream evicted
// Xb from L3 (router runs first); clean read lines re-allocate in the
// memory-side L3 and persist across the dispatch boundary, so GEMM1's
// token-gather A-loads hit L3 (~200-300cy) instead of HBM (~900cy). asm sink
// keeps the loads live (rule 17). Cost ~3us, overlapped with fill's
// latency-bound 32 blocks.
__global__ __launch_bounds__(256) void fill_kernel(
    const int* __restrict__ topk_i,
    const int* __restrict__ pc_partial,
    const float* __restrict__ pp_partial,
    const unsigned short* __restrict__ Xb,
    int* __restrict__ counts, int* __restrict__ offsets,
    float* __restrict__ aux_out,
    int* __restrict__ token_list,
    int* __restrict__ slot_of) {
  int tid = threadIdx.x;
  if (blockIdx.x >= NFILL) {
    // ---- Xb warm path: 16 MB / 64 blocks = 256 KB per block ----
    int w = blockIdx.x - NFILL;
    const unsigned short* src = Xb + (long)w * ((long)T_TOKENS * DIM / NWARM);
    #pragma unroll 4
    for (int i = 0; i < 64; i++) {
      short8 v = *(const short8*)(src + (long)(i * 256 + tid) * 8);
      asm volatile("" :: "v"(v));   // keep load live (no DCE)
    }
    return;
  }

  __shared__ int sc[32][NEXP];    // full-range partials
  __shared__ int scp[32][NEXP];   // prefix-range partials
  __shared__ float sp[32][NEXP];
  __shared__ int scnt[NEXP];
  __shared__ int soff[NEXP];
  __shared__ int sprefix[NEXP];
  __shared__ int swc[4][NEXP];    // per-wave per-expert assignment counts
  bool b0 = (blockIdx.x == 0);
  int rbLimit = blockIdx.x * (256 / RTOK);   // router blocks before this block
  {
    int e = tid & 7, chunk = tid >> 3;  // 32 chunks of router blocks
    int cs = 0, cp = 0; float ps = 0.f;
    for (int b = chunk; b < RBLOCKS; b += 32) {
      int v = pc_partial[b * NEXP + e];
      cs += v;
      if (b < rbLimit) cp += v;
      if (b0) ps += pp_partial[b * NEXP + e];
    }
    sc[chunk][e] = cs; scp[chunk][e] = cp;
    if (b0) sp[chunk][e] = ps;
  }
  __syncthreads();
  if (tid < NEXP) {
    int c = 0, p = 0;
    #pragma unroll
    for (int ch = 0; ch < 32; ch++) { c += sc[ch][tid]; p += scp[ch][tid]; }
    scnt[tid] = c; sprefix[tid] = p;
  }
  __syncthreads();
  if (tid == 0) {
    int off = 0;
    #pragma unroll
    for (int e = 0; e < NEXP; e++) { soff[e] = off; off += scnt[e]; }
    if (b0) {
      float prs[NEXP];
      #pragma unroll
      for (int e = 0; e < NEXP; e++) {
        prs[e] = 0.f;
        #pragma unroll
        for (int ch = 0; ch < 32; ch++) prs[e] += sp[ch][e];
      }
      int total = 0;
      #pragma unroll
      for (int e = 0; e < NEXP; e++) total += scnt[e];
      float inv_total = 1.f / (float)(total > 0 ? total : 1);
      float aux = 0.f;
      #pragma unroll
      for (int e = 0; e < NEXP; e++) {
        counts[e] = scnt[e];
        offsets[e] = soff[e];
        float importance = prs[e] / (float)T_TOKENS;
        float load = (float)scnt[e] * inv_total;
        aux += importance * load;
      }
      *aux_out = (float)NEXP * aux;
    }
  }
  __syncthreads();

  int t = blockIdx.x * 256 + tid;
  int wid = tid >> 6, lane = tid & 63;
  int e0 = topk_i[2 * t], e1 = topk_i[2 * t + 1];
  unsigned long long below = (1ULL << lane) - 1ULL;

  // per-wave per-expert counts
  {
    int cw[NEXP];
    #pragma unroll
    for (int eid = 0; eid < NEXP; eid++) {
      unsigned long long m0 = __ballot(e0 == eid);
      unsigned long long m1 = __ballot(e1 == eid);
      cw[eid] = __popcll(m0) + __popcll(m1);
    }
    if (lane == 0) {
      #pragma unroll
      for (int eid = 0; eid < NEXP; eid++) swc[wid][eid] = cw[eid];
    }
  }
  __syncthreads();

  int slot0 = 0, slot1 = 0;
  #pragma unroll
  for (int eid = 0; eid < NEXP; eid++) {
    unsigned long long m0 = __ballot(e0 == eid);
    unsigned long long m1 = __ballot(e1 == eid);
    int wbase = 0;
    #pragma unroll
    for (int w = 0; w < 4; w++) if (w < wid) wbase += swc[w][eid];
    int base = soff[eid] + sprefix[eid] + wbase;
    if (e0 == eid) slot0 = base + __popcll(m0 & below);
    if (e1 == eid) slot1 = base + __popcll(m0) + __popcll(m1 & below);
  }
  token_list[slot0] = t;
  token_list[slot1] = t;
  slot_of[2 * t] = slot0;
  slot_of[2 * t + 1] = slot1;
}

// ------- grouped GEMM: 128x128 tile, 16x16x32 MFMA, async LDS staging ------
// Proven m97-style structure (34% MfmaUtil, 0 bank conflicts) — plateau of
// this structure per R0-R4; 8-phase ports failed twice (24% MfmaUtil).
// xcd = expert swizzle (blockIdx & 7): each XCD's private L2 keeps its
// expert's whole B panel (4 MB bf16) resident.
template<bool GELU, bool GATHER, int NXN>
__global__ __launch_bounds__(256, 4) void gemm_kernel(
    const unsigned short* __restrict__ Abase,  // bf16 [*, K]
    const unsigned short* __restrict__ BT,     // bf16 [E][N][K]
    const float* __restrict__ bias,            // fp32 [E][N]
    unsigned short* __restrict__ Cout,         // bf16 [NASSIGN][N]
    const int* __restrict__ counts,
    const int* __restrict__ offsets,
    const int* __restrict__ token_list,
    int K, int N) {
  int flat = blockIdx.x;
  int e = flat & 7;          // xcd-local expert
  int q = flat >> 3;
  int n_idx = q % NXN;
  int mtile = q / NXN;
  int cnt = counts[e];
  if (mtile * 128 >= cnt) return;
  int rowbase = offsets[e];
  int n0 = n_idx * 128;
  int tid = threadIdx.x;
  int wid = tid >> 6, lane = tid & 63;

  __shared__ unsigned short As[128 * BK];
  __shared__ unsigned short Bs[128 * BK];

  // staging: wave w stages rows [32w, 32w+32), 4 instrs x (8 rows x 8 chunks)
  const unsigned short* asrc[4];
  const unsigned short* bsrc[4];
  #pragma unroll
  for (int j = 0; j < 4; j++) {
    int r = wid * 32 + j * 8 + (lane >> 3);  // tile row 0..127
    int p = lane & 7;                        // 16B chunk in lane-linear dest
    int swz = ((p ^ (r & 7)) * 8);           // source element offset in row
    long arow;
    if (GATHER) {
      int rl = mtile * 128 + r;
      int t = token_list[rowbase + min(rl, cnt - 1)];
      arow = (long)t * K;
    } else {
      int rr = rowbase + min(mtile * 128 + r, cnt - 1);
      arow = (long)rr * K;
    }
    asrc[j] = Abase + arow + swz;
    bsrc[j] = BT + ((long)e * N + n0 + r) * K + swz;
  }

  // wave tile: 64x64 via 4x4 frags of 16x16
  int wr = (wid >> 1) * 64, wc = (wid & 1) * 64;
  int lr = lane & 15, lq = lane >> 4;

  // precomputed LDS frag offsets (k0-invariant)
  int aoff[4][2], boff[4][2];
  #pragma unroll
  for (int im = 0; im < 4; im++) {
    int r = wr + im * 16 + lr;
    #pragma unroll
    for (int kk = 0; kk < 2; kk++) {
      int c = kk * 4 + lq;
      aoff[im][kk] = r * BK + ((c ^ (r & 7)) * 8);
    }
  }
  #pragma unroll
  for (int in = 0; in < 4; in++) {
    int r = wc + in * 16 + lr;
    #pragma unroll
    for (int kk = 0; kk < 2; kk++) {
      int c = kk * 4 + lq;
      boff[in][kk] = r * BK + ((c ^ (r & 7)) * 8);
    }
  }

  floatx4 zero = {0.f, 0.f, 0.f, 0.f};
  floatx4 acc[4][4];
  #pragma unroll
  for (int im = 0; im < 4; im++)
    #pragma unroll
    for (int in = 0; in < 4; in++) acc[im][in] = zero;

  for (int k0 = 0; k0 < K; k0 += BK) {
    #pragma unroll
    for (int j = 0; j < 4; j++) {
      int dst = (wid * 32 + j * 8) * BK;  // element offset of instr dest
      __builtin_amdgcn_global_load_lds((gbl_void*)(asrc[j] + k0),
                                       (lds_void*)&As[dst], 16, 0, 0);
      __builtin_amdgcn_global_load_lds((gbl_void*)(bsrc[j] + k0),
                                       (lds_void*)&Bs[dst], 16, 0, 0);
    }
    __syncthreads();
    #pragma unroll
    for (int kk = 0; kk < 2; kk++) {
      short8 af[4], bf[4];
      #pragma unroll
      for (int im = 0; im < 4; im++) af[im] = *(const short8*)&As[aoff[im][kk]];
      #pragma unroll
      for (int in = 0; in < 4; in++) bf[in] = *(const short8*)&Bs[boff[in][kk]];
      #pragma unroll
      for (int im = 0; im < 4; im++)
        #pragma unroll
        for (int in = 0; in < 4; in++)
          acc[im][in] = __builtin_amdgcn_mfma_f32_16x16x32_bf16(
              af[im], bf[in], acc[im][in], 0, 0, 0);
    }
    __syncthreads();
  }

  // epilogue: D layout col=lane&15, row=(lane>>4)*4+reg  [m89/m91]
  float bv[4];
  #pragma unroll
  for (int in = 0; in < 4; in++)
    bv[in] = bias[(long)e * N + n0 + wc + in * 16 + lr];
  #pragma unroll
  for (int im = 0; im < 4; im++) {
    int rbase = mtile * 128 + wr + im * 16 + lq * 4;
    #pragma unroll
    for (int j = 0; j < 4; j++) {
      int r = rbase + j;
      if (r < cnt) {
        long rowoff = (long)(rowbase + r) * N;
        #pragma unroll
        for (int in = 0; in < 4; in++) {
          int col = n0 + wc + in * 16 + lr;
          float v = acc[im][in][j] + bv[in];
          if (GELU) v = gelu_fast(v);
          Cout[rowoff + col] = f2bf(v);
        }
      }
    }
  }
}

// ---------------- combine: out[t] = w0*Y[s0] + w1*Y[s1] ----------------
__global__ void combine_kernel(const unsigned short* __restrict__ Yb,
                               const int* __restrict__ slot_of,
                               const float* __restrict__ topk_w,
                               float* __restrict__ out) {
  int idx = blockIdx.x * 256 + threadIdx.x;  // T * (D/8) threads
  int t = idx >> 7;
  int d = (idx & 127) * 8;
  int s0 = slot_of[2 * t], s1 = slot_of[2 * t + 1];
  float w0 = topk_w[2 * t], w1 = topk_w[2 * t + 1];
  short8 y0 = *(const short8*)(Yb + (long)s0 * DIM + d);
  short8 y1 = *(const short8*)(Yb + (long)s1 * DIM + d);
  float o[8];
  #pragma unroll
  for (int j = 0; j < 8; j++)
    o[j] = w0 * bf2f((unsigned short)y0[j]) + w1 * bf2f((unsigned short)y1[j]);
  float4 lo = {o[0], o[1], o[2], o[3]};
  float4 hi = {o[4], o[5], o[6], o[7]};
  float* op = out + (long)t * DIM + d;
  *(float4*)op = lo;
  *(float4*)(op + 4) = hi;
}

extern "C" void kernel_launch(void* const* d_in, const int* in_sizes, int n_in,
                              void* d_out, int out_size, void* d_ws, size_t ws_size,
                              hipStream_t stream) {
  const float* x  = (const float*)d_in[0];   // [T, D]
  const float* Wr = (const float*)d_in[1];   // [D, E]
  const float* br = (const float*)d_in[2];   // [E]
  const float* W1 = (const float*)d_in[3];   // [E, D, H]
  const float* b1 = (const float*)d_in[4];   // [E, H]
  const float* W2 = (const float*)d_in[5];   // [E, H, D]
  const float* b2 = (const float*)d_in[6];   // [E, D]
  float* out = (float*)d_out;                // [T*D] ++ [1] aux

  char* ws = (char*)d_ws;
  const long XB_OFF  = 0;                                   // T*D bf16
  const long W1T_OFF = XB_OFF  + (long)T_TOKENS * DIM * 2;  // E*H*D bf16
  const long W2T_OFF = W1T_OFF + (long)NEXP * DIM * HDIM * 2;
  const long HB_OFF  = W2T_OFF + (long)NEXP * DIM * HDIM * 2; // NASSIGN*H bf16
  const long YB_OFF  = HB_OFF  + (long)NASSIGN * HDIM * 2;    // NASSIGN*D bf16
  const long META_OFF = YB_OFF + (long)NASSIGN * DIM * 2;

  unsigned short* Xb  = (unsigned short*)(ws + XB_OFF);
  unsigned short* W1T = (unsigned short*)(ws + W1T_OFF);
  unsigned short* W2T = (unsigned short*)(ws + W2T_OFF);
  unsigned short* Hb  = (unsigned short*)(ws + HB_OFF);
  unsigned short* Yb  = (unsigned short*)(ws + YB_OFF);

  char* meta = ws + META_OFF;
  int*   counts    = (int*)(meta + 0);
  int*   offsets   = (int*)(meta + 32);
  int*   topk_i    = (int*)(meta + 128);
  float* topk_w    = (float*)(meta + 128 + 65536);
  int*   token_list= (int*)(meta + 128 + 131072);
  int*   slot_of   = (int*)(meta + 128 + 196608);
  int*   pc_part   = (int*)(meta + 128 + 262144);           // [RBLOCKS][8]
  float* pp_part   = (float*)(meta + 128 + 262144 + 65536); // [RBLOCKS][8]

  // NOTE: no memset needed — fill is atomic-free (deterministic prefix slots)
  // and counts/offsets/aux are fully written by fill before any consumer.

  // 1. fused router (FIRST, hidden) + weight transpose (one dispatch)
  prep_kernel<<<TBLOCKS + RBLOCKS, 256, 0, stream>>>(
      W1, W2, W1T, W2T, x, Wr, br, Xb, topk_i, topk_w, pc_part, pp_part);
  // 2. fill token lists (deterministic) + aux loss + Xb L3 re-warm
  fill_kernel<<<NFILL + NWARM, 256, 0, stream>>>(
      topk_i, pc_part, pp_part, Xb, counts, offsets,
      out + (long)T_TOKENS * DIM, token_list, slot_of);
  // 3. expert GEMM 1: H = gelu(X @ W1 + b1)   M=counts, N=2048, K=1024
  gemm_kernel<true, true, HDIM / 128><<<NEXP * 64 * (HDIM / 128), 256, 0, stream>>>(
      Xb, W1T, b1, Hb, counts, offsets, token_list, DIM, HDIM);
  // 4. expert GEMM 2: Y = H @ W2 + b2         M=counts, N=1024, K=2048
  gemm_kernel<false, false, DIM / 128><<<NEXP * 64 * (DIM / 128), 256, 0, stream>>>(
      Hb, W2T, b2, Yb, counts, offsets, nullptr, HDIM, DIM);
  // 5. combine
  combine_kernel<<<T_TOKENS * (DIM / 8) / 256, 256, 0, stream>>>(
      Yb, slot_of, topk_w, out);
}

// Round 8
// 385.360 us; speedup vs baseline: 1.0287x; 1.0287x over previous
//
#include <hip/hip_runtime.h>
#include <math.h>

// Problem constants (B=4,S=2048,D=1024,H=2048,E=8, top-2)
#define T_TOKENS 8192
#define DIM      1024
#define HDIM     2048
#define NEXP     8
#define NASSIGN  16384   // T_TOKENS * 2
#define RTOK     16      // tokens per router block
#define RBLOCKS  (T_TOKENS / RTOK)
#define BK       64      // GEMM K-tile
#define SWSTRIDE 1028    // router sW leading dim (breaks 8-way store conflict)
#define TBLOCKS  8192    // transpose blocks in prep_kernel
#define NFILL    (T_TOKENS / 256)   // 32 fill blocks
#define NWARM    256                // Xb warm blocks appended to fill grid

typedef __attribute__((ext_vector_type(8))) short short8;
typedef __attribute__((ext_vector_type(4))) float floatx4;
typedef __attribute__((address_space(3))) void lds_void;
typedef const __attribute__((address_space(1))) void gbl_void;

__device__ __forceinline__ unsigned short f2bf(float f) {
  unsigned u = __float_as_uint(f);
  u += 0x7fffu + ((u >> 16) & 1u);   // RNE
  return (unsigned short)(u >> 16);
}
__device__ __forceinline__ float bf2f(unsigned short h) {
  return __uint_as_float(((unsigned)h) << 16);
}

// fast GELU: v * sigmoid(1.5958*(v + 0.044715 v^3)); max abs err ~1e-3 vs erf
__device__ __forceinline__ float gelu_fast(float v) {
  float u = 1.5957691216057308f * v * fmaf(0.044715f * v, v, 1.0f);
  return v / (1.f + __expf(-u));
}

// ------- prep: fused {router FIRST} + {W1,W2 transpose+convert} -----------
// R5/R6 A/B resolved: router is a ~20us VALU-heavy job. Placed LAST it runs
// solo (serialized tail, R6); placed FIRST it hides fully under the BW-bound
// transpose, but the transpose stream then evicts the early-written Xb from
// L3 -> GEMM1 gather eats HBM latency (R5: GEMM1 91.6->108). Resolution:
// router FIRST + a cheap Xb L3 re-warm in the fill dispatch (below). R7
// confirmed the warm restores GEMM1 to 92us/34% MfmaUtil.
__global__ __launch_bounds__(256) void prep_kernel(
    const float* __restrict__ W1, const float* __restrict__ W2,
    unsigned short* __restrict__ W1T, unsigned short* __restrict__ W2T,
    const float* __restrict__ x, const float* __restrict__ Wr,
    const float* __restrict__ br, unsigned short* __restrict__ Xb,
    int* __restrict__ topk_i, float* __restrict__ topk_w,
    int* __restrict__ pc_partial,      // [RBLOCKS][NEXP]
    float* __restrict__ pp_partial) {  // [RBLOCKS][NEXP]
  __shared__ float smem[NEXP * SWSTRIDE + 64];  // 33.2 KB union
  int rb = blockIdx.x;
  int tid = threadIdx.x;

  if (rb >= RBLOCKS) {
    // ---------------- transpose path ----------------
    float (*tile)[65] = (float(*)[65])smem;
    int b = rb - RBLOCKS;
    const float* inp; unsigned short* outp; int R, C, r0, c0;
    if (b < 4096) {                       // W1: R=1024, C=2048; 512 tiles/exp
      int e = b >> 9, t = b & 511;
      R = DIM; C = HDIM;
      c0 = (t & 31) * 64; r0 = (t >> 5) * 64;
      long eb = (long)e * R * C;
      inp = W1 + eb; outp = W1T + eb;
    } else {                              // W2: R=2048, C=1024
      int bb = b - 4096;
      int e = bb >> 9, t = bb & 511;
      R = HDIM; C = DIM;
      c0 = (t & 15) * 64; r0 = (t >> 4) * 64;
      long eb = (long)e * R * C;
      inp = W2 + eb; outp = W2T + eb;
    }
    int rr = tid >> 4, c4 = (tid & 15) * 4;
    #pragma unroll
    for (int i = 0; i < 4; i++) {
      float4 v = *(const float4*)(inp + (long)(r0 + rr + i * 16) * C + c0 + c4);
      tile[rr + i * 16][c4 + 0] = v.x;
      tile[rr + i * 16][c4 + 1] = v.y;
      tile[rr + i * 16][c4 + 2] = v.z;
      tile[rr + i * 16][c4 + 3] = v.w;
    }
    __syncthreads();
    // 512 short8 stores, 2/thread: s -> col c = s>>3, row-block rq = (s&7)*8
    #pragma unroll
    for (int j = 0; j < 2; j++) {
      int s = tid * 2 + j;
      int c = s >> 3;
      int rq = (s & 7) * 8;
      short8 ov;
      #pragma unroll
      for (int i = 0; i < 8; i++) ov[i] = (short)f2bf(tile[rq + i][c]);
      *(short8*)(outp + (long)(c0 + c) * R + r0 + rq) = ov;
    }
    return;
  }

  // ---------------- router path (FIRST: hidden under transpose) ----------
  int bid = rb;
  float* sW = smem;                                   // [NEXP*SWSTRIDE]
  float (*sP)[NEXP] = (float(*)[NEXP])(smem + NEXP * SWSTRIDE);
  int   (*sC)[NEXP] = (int(*)[NEXP])(smem + NEXP * SWSTRIDE + 32);
  for (int i = tid; i < NEXP * DIM; i += 256)   // coalesced load, spread banks
    sW[(i & 7) * SWSTRIDE + (i >> 3)] = Wr[i];
  __syncthreads();
  int wid = tid >> 6, lane = tid & 63;
  float pacc[NEXP]; int cacc[NEXP];
  #pragma unroll
  for (int e = 0; e < NEXP; e++) { pacc[e] = 0.f; cacc[e] = 0; }
  #pragma unroll
  for (int it = 0; it < 4; it++) {
    int t = bid * RTOK + wid * 4 + it;
    const float* xp = x + (long)t * DIM;
    unsigned short* xbp = Xb + (long)t * DIM;
    float acc[NEXP];
    #pragma unroll
    for (int e = 0; e < NEXP; e++) acc[e] = 0.f;
    #pragma unroll
    for (int i = 0; i < 4; i++) {
      int off = i * 256 + lane * 4;
      float4 v = *(const float4*)(xp + off);
      ushort4 o;
      o.x = f2bf(v.x); o.y = f2bf(v.y); o.z = f2bf(v.z); o.w = f2bf(v.w);
      *(ushort4*)(xbp + off) = o;
      #pragma unroll
      for (int e = 0; e < NEXP; e++) {
        float4 w = *(const float4*)&sW[e * SWSTRIDE + off];
        acc[e] += v.x * w.x + v.y * w.y + v.z * w.z + v.w * w.w;
      }
    }
    #pragma unroll
    for (int e = 0; e < NEXP; e++) {
      #pragma unroll
      for (int off = 32; off; off >>= 1) acc[e] += __shfl_xor(acc[e], off, 64);
    }
    if (lane == 0) {
      float l[NEXP];
      #pragma unroll
      for (int e = 0; e < NEXP; e++) l[e] = acc[e] + br[e];
      float mx = l[0];
      #pragma unroll
      for (int e = 1; e < NEXP; e++) mx = fmaxf(mx, l[e]);
      float p[NEXP], s = 0.f;
      #pragma unroll
      for (int e = 0; e < NEXP; e++) { p[e] = __expf(l[e] - mx); s += p[e]; }
      float inv = 1.f / s;
      #pragma unroll
      for (int e = 0; e < NEXP; e++) p[e] *= inv;
      // top-2, lowest index wins ties (matches lax.top_k)
      int i1 = 0;
      #pragma unroll
      for (int e = 1; e < NEXP; e++) if (l[e] > l[i1]) i1 = e;
      int i2 = (i1 == 0) ? 1 : 0;
      #pragma unroll
      for (int e = 0; e < NEXP; e++)
        if (e != i1 && l[e] > l[i2]) i2 = e;
      float s2 = fmaxf(p[i1] + p[i2], 1e-9f);
      topk_i[2 * t] = i1; topk_i[2 * t + 1] = i2;
      topk_w[2 * t] = p[i1] / s2; topk_w[2 * t + 1] = p[i2] / s2;
      #pragma unroll
      for (int e = 0; e < NEXP; e++) {
        pacc[e] += p[e];
        cacc[e] += (e == i1 || e == i2) ? 1 : 0;
      }
    }
  }
  if (lane == 0) {
    #pragma unroll
    for (int e = 0; e < NEXP; e++) { sP[wid][e] = pacc[e]; sC[wid][e] = cacc[e]; }
  }
  __syncthreads();
  if (tid < NEXP) {
    float ps = 0.f; int cs = 0;
    #pragma unroll
    for (int w = 0; w < 4; w++) { ps += sP[w][tid]; cs += sC[w][tid]; }
    pp_partial[bid * NEXP + tid] = ps;
    pc_partial[bid * NEXP + tid] = cs;
  }
}

// ------ fill token lists (blocks 0..31) + Xb L3 re-warm (blocks 32..287) --
// Fill: deterministic prefix slots, no atomics, no memset (R5, kept).
// Warm: R7 lesson — per-iteration asm-volatile sinks SERIALIZE the loads
// (each volatile asm is an ordering point -> load/waitcnt(0)/asm per iter ->
// 64 dependent HBM round trips ~ 24us). Fix: 256 blocks x 16 INDEPENDENT
// 16B loads/thread, XOR-accumulate, ONE sink at the end -> all loads in
// flight, bandwidth-bound ~3us overlapped with fill.
__global__ __launch_bounds__(256) void fill_kernel(
    const int* __restrict__ topk_i,
    const int* __restrict__ pc_partial,
    const float* __restrict__ pp_partial,
    const unsigned short* __restrict__ Xb,
    int* __restrict__ counts, int* __restrict__ offsets,
    float* __restrict__ aux_out,
    int* __restrict__ token_list,
    int* __restrict__ slot_of) {
  int tid = threadIdx.x;
  if (blockIdx.x >= NFILL) {
    // ---- Xb warm path: 16 MB / 256 blocks = 64 KB per block ----
    int w = blockIdx.x - NFILL;
    const unsigned short* src = Xb + (long)w * ((long)T_TOKENS * DIM / NWARM);
    int acc = 0;
    #pragma unroll
    for (int i = 0; i < 16; i++) {
      short8 v = *(const short8*)(src + (long)(i * 256 + tid) * 8);
      acc ^= (int)v[0] ^ (int)v[7];   // depend on load; all loads issue first
    }
    asm volatile("" :: "v"(acc));     // single sink: keep loads live, no DCE
    return;
  }

  __shared__ int sc[32][NEXP];    // full-range partials
  __shared__ int scp[32][NEXP];   // prefix-range partials
  __shared__ float sp[32][NEXP];
  __shared__ int scnt[NEXP];
  __shared__ int soff[NEXP];
  __shared__ int sprefix[NEXP];
  __shared__ int swc[4][NEXP];    // per-wave per-expert assignment counts
  bool b0 = (blockIdx.x == 0);
  int rbLimit = blockIdx.x * (256 / RTOK);   // router blocks before this block
  {
    int e = tid & 7, chunk = tid >> 3;  // 32 chunks of router blocks
    int cs = 0, cp = 0; float ps = 0.f;
    for (int b = chunk; b < RBLOCKS; b += 32) {
      int v = pc_partial[b * NEXP + e];
      cs += v;
      if (b < rbLimit) cp += v;
      if (b0) ps += pp_partial[b * NEXP + e];
    }
    sc[chunk][e] = cs; scp[chunk][e] = cp;
    if (b0) sp[chunk][e] = ps;
  }
  __syncthreads();
  if (tid < NEXP) {
    int c = 0, p = 0;
    #pragma unroll
    for (int ch = 0; ch < 32; ch++) { c += sc[ch][tid]; p += scp[ch][tid]; }
    scnt[tid] = c; sprefix[tid] = p;
  }
  __syncthreads();
  if (tid == 0) {
    int off = 0;
    #pragma unroll
    for (int e = 0; e < NEXP; e++) { soff[e] = off; off += scnt[e]; }
    if (b0) {
      float prs[NEXP];
      #pragma unroll
      for (int e = 0; e < NEXP; e++) {
        prs[e] = 0.f;
        #pragma unroll
        for (int ch = 0; ch < 32; ch++) prs[e] += sp[ch][e];
      }
      int total = 0;
      #pragma unroll
      for (int e = 0; e < NEXP; e++) total += scnt[e];
      float inv_total = 1.f / (float)(total > 0 ? total : 1);
      float aux = 0.f;
      #pragma unroll
      for (int e = 0; e < NEXP; e++) {
        counts[e] = scnt[e];
        offsets[e] = soff[e];
        float importance = prs[e] / (float)T_TOKENS;
        float load = (float)scnt[e] * inv_total;
        aux += importance * load;
      }
      *aux_out = (float)NEXP * aux;
    }
  }
  __syncthreads();

  int t = blockIdx.x * 256 + tid;
  int wid = tid >> 6, lane = tid & 63;
  int e0 = topk_i[2 * t], e1 = topk_i[2 * t + 1];
  unsigned long long below = (1ULL << lane) - 1ULL;

  // per-wave per-expert counts
  {
    int cw[NEXP];
    #pragma unroll
    for (int eid = 0; eid < NEXP; eid++) {
      unsigned long long m0 = __ballot(e0 == eid);
      unsigned long long m1 = __ballot(e1 == eid);
      cw[eid] = __popcll(m0) + __popcll(m1);
    }
    if (lane == 0) {
      #pragma unroll
      for (int eid = 0; eid < NEXP; eid++) swc[wid][eid] = cw[eid];
    }
  }
  __syncthreads();

  int slot0 = 0, slot1 = 0;
  #pragma unroll
  for (int eid = 0; eid < NEXP; eid++) {
    unsigned long long m0 = __ballot(e0 == eid);
    unsigned long long m1 = __ballot(e1 == eid);
    int wbase = 0;
    #pragma unroll
    for (int w = 0; w < 4; w++) if (w < wid) wbase += swc[w][eid];
    int base = soff[eid] + sprefix[eid] + wbase;
    if (e0 == eid) slot0 = base + __popcll(m0 & below);
    if (e1 == eid) slot1 = base + __popcll(m0) + __popcll(m1 & below);
  }
  token_list[slot0] = t;
  token_list[slot1] = t;
  slot_of[2 * t] = slot0;
  slot_of[2 * t + 1] = slot1;
}

// ------- grouped GEMM: 128x128 tile, 16x16x32 MFMA, async LDS staging ------
// Proven m97-style structure (34% MfmaUtil, 0 bank conflicts) — plateau of
// this structure per R0-R4; 8-phase ports failed twice (24% MfmaUtil).
// xcd = expert swizzle (blockIdx & 7): each XCD's private L2 keeps its
// expert's whole B panel (4 MB bf16) resident.
template<bool GELU, bool GATHER, int NXN>
__global__ __launch_bounds__(256, 4) void gemm_kernel(
    const unsigned short* __restrict__ Abase,  // bf16 [*, K]
    const unsigned short* __restrict__ BT,     // bf16 [E][N][K]
    const float* __restrict__ bias,            // fp32 [E][N]
    unsigned short* __restrict__ Cout,         // bf16 [NASSIGN][N]
    const int* __restrict__ counts,
    const int* __restrict__ offsets,
    const int* __restrict__ token_list,
    int K, int N) {
  int flat = blockIdx.x;
  int e = flat & 7;          // xcd-local expert
  int q = flat >> 3;
  int n_idx = q % NXN;
  int mtile = q / NXN;
  int cnt = counts[e];
  if (mtile * 128 >= cnt) return;
  int rowbase = offsets[e];
  int n0 = n_idx * 128;
  int tid = threadIdx.x;
  int wid = tid >> 6, lane = tid & 63;

  __shared__ unsigned short As[128 * BK];
  __shared__ unsigned short Bs[128 * BK];

  // staging: wave w stages rows [32w, 32w+32), 4 instrs x (8 rows x 8 chunks)
  const unsigned short* asrc[4];
  const unsigned short* bsrc[4];
  #pragma unroll
  for (int j = 0; j < 4; j++) {
    int r = wid * 32 + j * 8 + (lane >> 3);  // tile row 0..127
    int p = lane & 7;                        // 16B chunk in lane-linear dest
    int swz = ((p ^ (r & 7)) * 8);           // source element offset in row
    long arow;
    if (GATHER) {
      int rl = mtile * 128 + r;
      int t = token_list[rowbase + min(rl, cnt - 1)];
      arow = (long)t * K;
    } else {
      int rr = rowbase + min(mtile * 128 + r, cnt - 1);
      arow = (long)rr * K;
    }
    asrc[j] = Abase + arow + swz;
    bsrc[j] = BT + ((long)e * N + n0 + r) * K + swz;
  }

  // wave tile: 64x64 via 4x4 frags of 16x16
  int wr = (wid >> 1) * 64, wc = (wid & 1) * 64;
  int lr = lane & 15, lq = lane >> 4;

  // precomputed LDS frag offsets (k0-invariant)
  int aoff[4][2], boff[4][2];
  #pragma unroll
  for (int im = 0; im < 4; im++) {
    int r = wr + im * 16 + lr;
    #pragma unroll
    for (int kk = 0; kk < 2; kk++) {
      int c = kk * 4 + lq;
      aoff[im][kk] = r * BK + ((c ^ (r & 7)) * 8);
    }
  }
  #pragma unroll
  for (int in = 0; in < 4; in++) {
    int r = wc + in * 16 + lr;
    #pragma unroll
    for (int kk = 0; kk < 2; kk++) {
      int c = kk * 4 + lq;
      boff[in][kk] = r * BK + ((c ^ (r & 7)) * 8);
    }
  }

  floatx4 zero = {0.f, 0.f, 0.f, 0.f};
  floatx4 acc[4][4];
  #pragma unroll
  for (int im = 0; im < 4; im++)
    #pragma unroll
    for (int in = 0; in < 4; in++) acc[im][in] = zero;

  for (int k0 = 0; k0 < K; k0 += BK) {
    #pragma unroll
    for (int j = 0; j < 4; j++) {
      int dst = (wid * 32 + j * 8) * BK;  // element offset of instr dest
      __builtin_amdgcn_global_load_lds((gbl_void*)(asrc[j] + k0),
                                       (lds_void*)&As[dst], 16, 0, 0);
      __builtin_amdgcn_global_load_lds((gbl_void*)(bsrc[j] + k0),
                                       (lds_void*)&Bs[dst], 16, 0, 0);
    }
    __syncthreads();
    #pragma unroll
    for (int kk = 0; kk < 2; kk++) {
      short8 af[4], bf[4];
      #pragma unroll
      for (int im = 0; im < 4; im++) af[im] = *(const short8*)&As[aoff[im][kk]];
      #pragma unroll
      for (int in = 0; in < 4; in++) bf[in] = *(const short8*)&Bs[boff[in][kk]];
      #pragma unroll
      for (int im = 0; im < 4; im++)
        #pragma unroll
        for (int in = 0; in < 4; in++)
          acc[im][in] = __builtin_amdgcn_mfma_f32_16x16x32_bf16(
              af[im], bf[in], acc[im][in], 0, 0, 0);
    }
    __syncthreads();
  }

  // epilogue: D layout col=lane&15, row=(lane>>4)*4+reg  [m89/m91]
  float bv[4];
  #pragma unroll
  for (int in = 0; in < 4; in++)
    bv[in] = bias[(long)e * N + n0 + wc + in * 16 + lr];
  #pragma unroll
  for (int im = 0; im < 4; im++) {
    int rbase = mtile * 128 + wr + im * 16 + lq * 4;
    #pragma unroll
    for (int j = 0; j < 4; j++) {
      int r = rbase + j;
      if (r < cnt) {
        long rowoff = (long)(rowbase + r) * N;
        #pragma unroll
        for (int in = 0; in < 4; in++) {
          int col = n0 + wc + in * 16 + lr;
          float v = acc[im][in][j] + bv[in];
          if (GELU) v = gelu_fast(v);
          Cout[rowoff + col] = f2bf(v);
        }
      }
    }
  }
}

// ---------------- combine: out[t] = w0*Y[s0] + w1*Y[s1] ----------------
__global__ void combine_kernel(const unsigned short* __restrict__ Yb,
                               const int* __restrict__ slot_of,
                               const float* __restrict__ topk_w,
                               float* __restrict__ out) {
  int idx = blockIdx.x * 256 + threadIdx.x;  // T * (D/8) threads
  int t = idx >> 7;
  int d = (idx & 127) * 8;
  int s0 = slot_of[2 * t], s1 = slot_of[2 * t + 1];
  float w0 = topk_w[2 * t], w1 = topk_w[2 * t + 1];
  short8 y0 = *(const short8*)(Yb + (long)s0 * DIM + d);
  short8 y1 = *(const short8*)(Yb + (long)s1 * DIM + d);
  float o[8];
  #pragma unroll
  for (int j = 0; j < 8; j++)
    o[j] = w0 * bf2f((unsigned short)y0[j]) + w1 * bf2f((unsigned short)y1[j]);
  float4 lo = {o[0], o[1], o[2], o[3]};
  float4 hi = {o[4], o[5], o[6], o[7]};
  float* op = out + (long)t * DIM + d;
  *(float4*)op = lo;
  *(float4*)(op + 4) = hi;
}

extern "C" void kernel_launch(void* const* d_in, const int* in_sizes, int n_in,
                              void* d_out, int out_size, void* d_ws, size_t ws_size,
                              hipStream_t stream) {
  const float* x  = (const float*)d_in[0];   // [T, D]
  const float* Wr = (const float*)d_in[1];   // [D, E]
  const float* br = (const float*)d_in[2];   // [E]
  const float* W1 = (const float*)d_in[3];   // [E, D, H]
  const float* b1 = (const float*)d_in[4];   // [E, H]
  const float* W2 = (const float*)d_in[5];   // [E, H, D]
  const float* b2 = (const float*)d_in[6];   // [E, D]
  float* out = (float*)d_out;                // [T*D] ++ [1] aux

  char* ws = (char*)d_ws;
  const long XB_OFF  = 0;                                   // T*D bf16
  const long W1T_OFF = XB_OFF  + (long)T_TOKENS * DIM * 2;  // E*H*D bf16
  const long W2T_OFF = W1T_OFF + (long)NEXP * DIM * HDIM * 2;
  const long HB_OFF  = W2T_OFF + (long)NEXP * DIM * HDIM * 2; // NASSIGN*H bf16
  const long YB_OFF  = HB_OFF  + (long)NASSIGN * HDIM * 2;    // NASSIGN*D bf16
  const long META_OFF = YB_OFF + (long)NASSIGN * DIM * 2;

  unsigned short* Xb  = (unsigned short*)(ws + XB_OFF);
  unsigned short* W1T = (unsigned short*)(ws + W1T_OFF);
  unsigned short* W2T = (unsigned short*)(ws + W2T_OFF);
  unsigned short* Hb  = (unsigned short*)(ws + HB_OFF);
  unsigned short* Yb  = (unsigned short*)(ws + YB_OFF);

  char* meta = ws + META_OFF;
  int*   counts    = (int*)(meta + 0);
  int*   offsets   = (int*)(meta + 32);
  int*   topk_i    = (int*)(meta + 128);
  float* topk_w    = (float*)(meta + 128 + 65536);
  int*   token_list= (int*)(meta + 128 + 131072);
  int*   slot_of   = (int*)(meta + 128 + 196608);
  int*   pc_part   = (int*)(meta + 128 + 262144);           // [RBLOCKS][8]
  float* pp_part   = (float*)(meta + 128 + 262144 + 65536); // [RBLOCKS][8]

  // NOTE: no memset needed — fill is atomic-free (deterministic prefix slots)
  // and counts/offsets/aux are fully written by fill before any consumer.

  // 1. fused router (FIRST, hidden) + weight transpose (one dispatch)
  prep_kernel<<<TBLOCKS + RBLOCKS, 256, 0, stream>>>(
      W1, W2, W1T, W2T, x, Wr, br, Xb, topk_i, topk_w, pc_part, pp_part);
  // 2. fill token lists (deterministic) + aux loss + Xb L3 re-warm (MLP fix)
  fill_kernel<<<NFILL + NWARM, 256, 0, stream>>>(
      topk_i, pc_part, pp_part, Xb, counts, offsets,
      out + (long)T_TOKENS * DIM, token_list, slot_of);
  // 3. expert GEMM 1: H = gelu(X @ W1 + b1)   M=counts, N=2048, K=1024
  gemm_kernel<true, true, HDIM / 128><<<NEXP * 64 * (HDIM / 128), 256, 0, stream>>>(
      Xb, W1T, b1, Hb, counts, offsets, token_list, DIM, HDIM);
  // 4. expert GEMM 2: Y = H @ W2 + b2         M=counts, N=1024, K=2048
  gemm_kernel<false, false, DIM / 128><<<NEXP * 64 * (DIM / 128), 256, 0, stream>>>(
      Hb, W2T, b2, Yb, counts, offsets, nullptr, HDIM, DIM);
  // 5. combine
  combine_kernel<<<T_TOKENS * (DIM / 8) / 256, 256, 0, stream>>>(
      Yb, slot_of, topk_w, out);
}